// Round 5
// baseline (831.382 us; speedup 1.0000x reference)
//
#include <hip/hip_runtime.h>

#define NUM_USERS 100000
#define NUM_ITEMS 200000
#define NNODES    300000   // NUM_USERS + NUM_ITEMS
#define EDIM      64
#define NEDGES    1200000
#define BATCH     4096

// One wave (64 lanes) per edge: lane d handles dim d.
// Read cur[src] coalesced (256B), atomicAdd into nxt[dst].
__global__ void scatter_add_k(const float* __restrict__ cur, float* __restrict__ nxt,
                              const int* __restrict__ src, const int* __restrict__ dst) {
    int w = (int)((blockIdx.x * blockDim.x + threadIdx.x) >> 6);
    int lane = threadIdx.x & 63;
    if (w >= NEDGES) return;
    int s = src[w];
    int d = dst[w];
    float v = cur[(size_t)s * EDIM + lane];
    atomicAdd(&nxt[(size_t)d * EDIM + lane], v);
}

// Accumulate the sampled rows (4096 users + 4096 items) of the current layer
// into a small accs[2*BATCH][64] buffer. first=1 initializes (overwrites poison).
__global__ void acc_batch_k(const float* __restrict__ cur, const int* __restrict__ users,
                            const int* __restrict__ items, float* __restrict__ accs, int first) {
    int t = (int)(blockIdx.x * blockDim.x + threadIdx.x);
    int row = t >> 6, lane = t & 63;
    if (row >= 2 * BATCH) return;
    int node = (row < BATCH) ? users[row] : (NUM_USERS + items[row - BATCH]);
    float v = cur[(size_t)node * EDIM + lane];
    size_t o = (size_t)row * EDIM + lane;
    if (first) accs[o] = v;
    else       accs[o] += v;
}

// Final: out[b] = (acc_u . acc_i) / 16   (final = acc/4 for each side)
__global__ void dot_out_k(const float* __restrict__ accs, float* __restrict__ out) {
    int t = (int)(blockIdx.x * blockDim.x + threadIdx.x);
    int b = t >> 6, lane = t & 63;
    if (b >= BATCH) return;
    float p = accs[(size_t)b * EDIM + lane] * accs[(size_t)(BATCH + b) * EDIM + lane];
    #pragma unroll
    for (int off = 32; off; off >>= 1) p += __shfl_down(p, off, 64);
    if (lane == 0) out[b] = p * (1.0f / 16.0f);
}

extern "C" void kernel_launch(void* const* d_in, const int* in_sizes, int n_in,
                              void* d_out, int out_size, void* d_ws, size_t ws_size,
                              hipStream_t stream) {
    const float* emb   = (const float*)d_in[0];
    const int*   edge  = (const int*)d_in[1];
    const int*   src   = edge;            // edge_index[0]
    const int*   dst   = edge + NEDGES;   // edge_index[1]
    const int*   users = (const int*)d_in[2];
    const int*   items = (const int*)d_in[3];
    float*       out   = (float*)d_out;

    const size_t bufBytes = (size_t)NNODES * EDIM * sizeof(float); // 76.8 MB
    float* bufA = (float*)d_ws;
    float* bufB = (float*)((char*)d_ws + bufBytes);
    float* accs = (float*)((char*)d_ws + 2 * bufBytes);            // 2 MB

    const dim3 blk(256);
    const int scatterBlocks = (NEDGES + 3) / 4;           // 4 waves/block, 1 edge/wave
    const int accBlocks     = (2 * BATCH * 64 + 255) / 256;
    const int dotBlocks     = (BATCH * 64 + 255) / 256;

    // acc = layer-0 (raw embedding) at sampled rows
    acc_batch_k<<<accBlocks, blk, 0, stream>>>(emb, users, items, accs, 1);

    const float* cur = emb;
    float* bufs[2] = {bufA, bufB};
    for (int l = 0; l < 3; ++l) {
        float* nxt = bufs[l & 1];
        hipMemsetAsync(nxt, 0, bufBytes, stream);
        scatter_add_k<<<scatterBlocks, blk, 0, stream>>>(cur, nxt, src, dst);
        acc_batch_k<<<accBlocks, blk, 0, stream>>>(nxt, users, items, accs, 0);
        cur = nxt;
    }

    dot_out_k<<<dotBlocks, blk, 0, stream>>>(accs, out);
}

// Round 6
// 428.601 us; speedup vs baseline: 1.9398x; 1.9398x over previous
//
#include <hip/hip_runtime.h>

#define NUM_USERS 100000
#define NUM_ITEMS 200000
#define NNODES    300000   // NUM_USERS + NUM_ITEMS
#define EDIM      64
#define NEDGES    1200000
#define BATCH     4096
#define CHUNK     1024
#define NCHUNKS   ((NNODES + CHUNK - 1) / CHUNK)   // 293

static inline size_t align256(size_t x) { return (x + 255) & ~(size_t)255; }

// ---------------- CSR build ----------------

__global__ void hist_k(const int* __restrict__ dst, int* __restrict__ counts) {
    int e = (int)(blockIdx.x * blockDim.x + threadIdx.x);
    if (e < NEDGES) atomicAdd(&counts[dst[e]], 1);
}

// Per-chunk exclusive scan (1024 elems/block, 4/thread) + chunk totals.
__global__ void scan_chunk_k(const int* __restrict__ counts, int* __restrict__ row_ptr,
                             int* __restrict__ chunk_tot) {
    __shared__ int sm[256];
    int t = threadIdx.x;
    int base = (int)blockIdx.x * CHUNK + t * 4;
    int v0 = (base + 0 < NNODES) ? counts[base + 0] : 0;
    int v1 = (base + 1 < NNODES) ? counts[base + 1] : 0;
    int v2 = (base + 2 < NNODES) ? counts[base + 2] : 0;
    int v3 = (base + 3 < NNODES) ? counts[base + 3] : 0;
    int ts = v0 + v1 + v2 + v3;
    sm[t] = ts;
    __syncthreads();
    for (int off = 1; off < 256; off <<= 1) {
        int x = (t >= off) ? sm[t - off] : 0;
        __syncthreads();
        sm[t] += x;
        __syncthreads();
    }
    int run = sm[t] - ts;   // exclusive prefix of this thread within chunk
    if (t == 255) chunk_tot[blockIdx.x] = sm[255];
    if (base + 0 < NNODES) row_ptr[base + 0] = run; run += v0;
    if (base + 1 < NNODES) row_ptr[base + 1] = run; run += v1;
    if (base + 2 < NNODES) row_ptr[base + 2] = run; run += v2;
    if (base + 3 < NNODES) row_ptr[base + 3] = run;
}

// Serial scan of 293 chunk totals (trivial); writes row_ptr[NNODES]=NEDGES.
__global__ void scan_tops_k(int* __restrict__ chunk_tot, int* __restrict__ row_ptr) {
    if (threadIdx.x == 0 && blockIdx.x == 0) {
        int run = 0;
        for (int c = 0; c < NCHUNKS; ++c) { int v = chunk_tot[c]; chunk_tot[c] = run; run += v; }
        row_ptr[NNODES] = run;
    }
}

__global__ void add_off_k(int* __restrict__ row_ptr, const int* __restrict__ chunk_tot) {
    int i = (int)(blockIdx.x * blockDim.x + threadIdx.x);
    if (i < NNODES) row_ptr[i] += chunk_tot[i / CHUNK];
}

__global__ void fill_k(const int* __restrict__ src, const int* __restrict__ dst,
                       const int* __restrict__ row_ptr, int* __restrict__ cursor,
                       int* __restrict__ ssrc) {
    int e = (int)(blockIdx.x * blockDim.x + threadIdx.x);
    if (e >= NEDGES) return;
    int d = dst[e];
    int pos = atomicAdd(&cursor[d], 1);
    ssrc[row_ptr[d] + pos] = src[e];
}

// ---------------- propagation (segmented sum, no atomics) ----------------

// One wave per node: sum cur rows of incoming srcs, one coalesced 256B write.
__global__ void prop_k(const float* __restrict__ cur, float* __restrict__ nxt,
                       const int* __restrict__ row_ptr, const int* __restrict__ ssrc) {
    int w = (int)((blockIdx.x * blockDim.x + threadIdx.x) >> 6);
    int lane = threadIdx.x & 63;
    if (w >= NNODES) return;
    int s0 = row_ptr[w], s1 = row_ptr[w + 1];
    float acc = 0.f;
    for (int e = s0; e < s1; ++e) {
        int s = ssrc[e];
        acc += cur[(size_t)s * EDIM + lane];
    }
    nxt[(size_t)w * EDIM + lane] = acc;
}

// Layer-3 only at the 8192 sampled rows, accumulated straight into accs.
__global__ void prop_sampled_k(const float* __restrict__ cur, const int* __restrict__ users,
                               const int* __restrict__ items, const int* __restrict__ row_ptr,
                               const int* __restrict__ ssrc, float* __restrict__ accs) {
    int w = (int)((blockIdx.x * blockDim.x + threadIdx.x) >> 6);
    int lane = threadIdx.x & 63;
    if (w >= 2 * BATCH) return;
    int node = (w < BATCH) ? users[w] : (NUM_USERS + items[w - BATCH]);
    int s0 = row_ptr[node], s1 = row_ptr[node + 1];
    float acc = 0.f;
    for (int e = s0; e < s1; ++e) acc += cur[(size_t)ssrc[e] * EDIM + lane];
    accs[(size_t)w * EDIM + lane] += acc;
}

// ---------------- sampled accumulation + output ----------------

__global__ void acc_batch_k(const float* __restrict__ cur, const int* __restrict__ users,
                            const int* __restrict__ items, float* __restrict__ accs, int first) {
    int t = (int)(blockIdx.x * blockDim.x + threadIdx.x);
    int row = t >> 6, lane = t & 63;
    if (row >= 2 * BATCH) return;
    int node = (row < BATCH) ? users[row] : (NUM_USERS + items[row - BATCH]);
    float v = cur[(size_t)node * EDIM + lane];
    size_t o = (size_t)row * EDIM + lane;
    if (first) accs[o] = v;
    else       accs[o] += v;
}

__global__ void dot_out_k(const float* __restrict__ accs, float* __restrict__ out) {
    int t = (int)(blockIdx.x * blockDim.x + threadIdx.x);
    int b = t >> 6, lane = t & 63;
    if (b >= BATCH) return;
    float p = accs[(size_t)b * EDIM + lane] * accs[(size_t)(BATCH + b) * EDIM + lane];
    #pragma unroll
    for (int off = 32; off; off >>= 1) p += __shfl_down(p, off, 64);
    if (lane == 0) out[b] = p * (1.0f / 16.0f);
}

// ---------------- fallback (baseline atomic path) ----------------

__global__ void scatter_add_k(const float* __restrict__ cur, float* __restrict__ nxt,
                              const int* __restrict__ src, const int* __restrict__ dst) {
    int w = (int)((blockIdx.x * blockDim.x + threadIdx.x) >> 6);
    int lane = threadIdx.x & 63;
    if (w >= NEDGES) return;
    float v = cur[(size_t)src[w] * EDIM + lane];
    atomicAdd(&nxt[(size_t)dst[w] * EDIM + lane], v);
}

extern "C" void kernel_launch(void* const* d_in, const int* in_sizes, int n_in,
                              void* d_out, int out_size, void* d_ws, size_t ws_size,
                              hipStream_t stream) {
    const float* emb   = (const float*)d_in[0];
    const int*   edge  = (const int*)d_in[1];
    const int*   src   = edge;            // edge_index[0]
    const int*   dst   = edge + NEDGES;   // edge_index[1]
    const int*   users = (const int*)d_in[2];
    const int*   items = (const int*)d_in[3];
    float*       out   = (float*)d_out;

    const size_t bufBytes = (size_t)NNODES * EDIM * sizeof(float); // 76.8 MB

    // workspace layout
    size_t off = 0;
    float* bufA = (float*)((char*)d_ws + off); off = align256(off + bufBytes);
    float* bufB = (float*)((char*)d_ws + off); off = align256(off + bufBytes);
    float* accs = (float*)((char*)d_ws + off); off = align256(off + (size_t)2 * BATCH * EDIM * sizeof(float));
    int* row_ptr   = (int*)((char*)d_ws + off); off = align256(off + (size_t)(NNODES + 1) * sizeof(int));
    int* counts    = (int*)((char*)d_ws + off); off = align256(off + (size_t)NNODES * sizeof(int));
    int* cursor    = (int*)((char*)d_ws + off); off = align256(off + (size_t)NNODES * sizeof(int));
    int* chunk_tot = (int*)((char*)d_ws + off); off = align256(off + (size_t)NCHUNKS * sizeof(int));
    int* ssrc      = (int*)((char*)d_ws + off); off = align256(off + (size_t)NEDGES * sizeof(int));
    const size_t needed = off;

    const dim3 blk(256);
    const int accBlocks = (2 * BATCH * 64 + 255) / 256;
    const int dotBlocks = (BATCH * 64 + 255) / 256;

    if (ws_size >= needed) {
        // ---- CSR build ----
        hipMemsetAsync(counts, 0, (size_t)NNODES * sizeof(int), stream);
        hipMemsetAsync(cursor, 0, (size_t)NNODES * sizeof(int), stream);
        hist_k<<<(NEDGES + 255) / 256, blk, 0, stream>>>(dst, counts);
        scan_chunk_k<<<NCHUNKS, blk, 0, stream>>>(counts, row_ptr, chunk_tot);
        scan_tops_k<<<1, 64, 0, stream>>>(chunk_tot, row_ptr);
        add_off_k<<<(NNODES + 255) / 256, blk, 0, stream>>>(row_ptr, chunk_tot);
        fill_k<<<(NEDGES + 255) / 256, blk, 0, stream>>>(src, dst, row_ptr, cursor, ssrc);

        // ---- layers ----
        const int propBlocks = (NNODES * 64 + 255) / 256;
        acc_batch_k<<<accBlocks, blk, 0, stream>>>(emb, users, items, accs, 1);      // layer 0
        prop_k<<<propBlocks, blk, 0, stream>>>(emb, bufA, row_ptr, ssrc);            // layer 1
        acc_batch_k<<<accBlocks, blk, 0, stream>>>(bufA, users, items, accs, 0);
        prop_k<<<propBlocks, blk, 0, stream>>>(bufA, bufB, row_ptr, ssrc);           // layer 2
        acc_batch_k<<<accBlocks, blk, 0, stream>>>(bufB, users, items, accs, 0);
        prop_sampled_k<<<(2 * BATCH * 64 + 255) / 256, blk, 0, stream>>>(            // layer 3 (sampled only)
            bufB, users, items, row_ptr, ssrc, accs);
        dot_out_k<<<dotBlocks, blk, 0, stream>>>(accs, out);
    } else {
        // ---- fallback: baseline atomic path (needs 2*bufBytes + accs) ----
        const int scatterBlocks = (NEDGES + 3) / 4;
        acc_batch_k<<<accBlocks, blk, 0, stream>>>(emb, users, items, accs, 1);
        const float* cur = emb;
        float* bufs[2] = {bufA, bufB};
        for (int l = 0; l < 3; ++l) {
            float* nxt = bufs[l & 1];
            hipMemsetAsync(nxt, 0, bufBytes, stream);
            scatter_add_k<<<scatterBlocks, blk, 0, stream>>>(cur, nxt, src, dst);
            acc_batch_k<<<accBlocks, blk, 0, stream>>>(nxt, users, items, accs, 0);
            cur = nxt;
        }
        dot_out_k<<<dotBlocks, blk, 0, stream>>>(accs, out);
    }
}

// Round 7
// 269.909 us; speedup vs baseline: 3.0802x; 1.5879x over previous
//
#include <hip/hip_runtime.h>

#define NUM_USERS 100000
#define NUM_ITEMS 200000
#define NNODES    300000   // NUM_USERS + NUM_ITEMS
#define EDIM      64
#define NEDGES    1200000
#define BATCH     4096
#define CHUNK     1024
#define NCHUNKS   ((NNODES + CHUNK - 1) / CHUNK)   // 293

static inline size_t align256(size_t x) { return (x + 255) & ~(size_t)255; }

// ---------------- CSR build ----------------

__global__ void hist_k(const int* __restrict__ dst, int* __restrict__ counts) {
    int e = (int)(blockIdx.x * blockDim.x + threadIdx.x);
    if (e < NEDGES) atomicAdd(&counts[dst[e]], 1);
}

__global__ void scan_chunk_k(const int* __restrict__ counts, int* __restrict__ row_ptr,
                             int* __restrict__ chunk_tot) {
    __shared__ int sm[256];
    int t = threadIdx.x;
    int base = (int)blockIdx.x * CHUNK + t * 4;
    int v0 = (base + 0 < NNODES) ? counts[base + 0] : 0;
    int v1 = (base + 1 < NNODES) ? counts[base + 1] : 0;
    int v2 = (base + 2 < NNODES) ? counts[base + 2] : 0;
    int v3 = (base + 3 < NNODES) ? counts[base + 3] : 0;
    int ts = v0 + v1 + v2 + v3;
    sm[t] = ts;
    __syncthreads();
    for (int off = 1; off < 256; off <<= 1) {
        int x = (t >= off) ? sm[t - off] : 0;
        __syncthreads();
        sm[t] += x;
        __syncthreads();
    }
    int run = sm[t] - ts;
    if (t == 255) chunk_tot[blockIdx.x] = sm[255];
    if (base + 0 < NNODES) row_ptr[base + 0] = run; run += v0;
    if (base + 1 < NNODES) row_ptr[base + 1] = run; run += v1;
    if (base + 2 < NNODES) row_ptr[base + 2] = run; run += v2;
    if (base + 3 < NNODES) row_ptr[base + 3] = run;
}

__global__ void scan_tops_k(int* __restrict__ chunk_tot, int* __restrict__ row_ptr) {
    if (threadIdx.x == 0 && blockIdx.x == 0) {
        int run = 0;
        for (int c = 0; c < NCHUNKS; ++c) { int v = chunk_tot[c]; chunk_tot[c] = run; run += v; }
        row_ptr[NNODES] = run;
    }
}

__global__ void add_off_k(int* __restrict__ row_ptr, const int* __restrict__ chunk_tot) {
    int i = (int)(blockIdx.x * blockDim.x + threadIdx.x);
    if (i < NNODES) row_ptr[i] += chunk_tot[i / CHUNK];
}

__global__ void fill_k(const int* __restrict__ src, const int* __restrict__ dst,
                       const int* __restrict__ row_ptr, int* __restrict__ cursor,
                       int* __restrict__ ssrc) {
    int e = (int)(blockIdx.x * blockDim.x + threadIdx.x);
    if (e >= NEDGES) return;
    int d = dst[e];
    int pos = atomicAdd(&cursor[d], 1);
    ssrc[row_ptr[d] + pos] = src[e];
}

// ---------------- frontier marking (race-free: each pass reads only flags
// finalized by a prior kernel; writes are plain =1 byte stores) ----------------

__global__ void mark_sampled_k(const int* __restrict__ users, const int* __restrict__ items,
                               unsigned char* __restrict__ mS) {
    int t = (int)(blockIdx.x * blockDim.x + threadIdx.x);
    if (t >= 2 * BATCH) return;
    int node = (t < BATCH) ? users[t] : (NUM_USERS + items[t - BATCH]);
    mS[node] = 1;
}

// mA[src] = 1 for edges into sampled nodes  (=> needL2 = mS | mA)
__global__ void markA_k(const int* __restrict__ src, const int* __restrict__ dst,
                        const unsigned char* __restrict__ mS, unsigned char* __restrict__ mA) {
    int e = (int)(blockIdx.x * blockDim.x + threadIdx.x);
    if (e >= NEDGES) return;
    if (mS[dst[e]]) mA[src[e]] = 1;
}

// mB[src] = 1 for edges into needL2 nodes  (=> needL1 = mS | mA | mB)
__global__ void markB_k(const int* __restrict__ src, const int* __restrict__ dst,
                        const unsigned char* __restrict__ mS, const unsigned char* __restrict__ mA,
                        unsigned char* __restrict__ mB) {
    int e = (int)(blockIdx.x * blockDim.x + threadIdx.x);
    if (e >= NEDGES) return;
    int d = dst[e];
    if (mS[d] | mA[d]) mB[src[e]] = 1;
}

// ---------------- propagation: segmented sum, 4-deep ILP, frontier-gated ----------------

__global__ void prop_k(const float* __restrict__ cur, float* __restrict__ nxt,
                       const int* __restrict__ row_ptr, const int* __restrict__ ssrc,
                       const unsigned char* __restrict__ f0, const unsigned char* __restrict__ f1,
                       const unsigned char* __restrict__ f2) {
    int w = (int)((blockIdx.x * blockDim.x + threadIdx.x) >> 6);
    int lane = threadIdx.x & 63;
    if (w >= NNODES) return;
    if (!(f0[w] | f1[w] | f2[w])) return;     // not needed at this layer
    int s0 = row_ptr[w], s1 = row_ptr[w + 1];
    float a0 = 0.f, a1 = 0.f, a2 = 0.f, a3 = 0.f;
    int e = s0;
    for (; e + 4 <= s1; e += 4) {
        int i0 = ssrc[e + 0], i1 = ssrc[e + 1], i2 = ssrc[e + 2], i3 = ssrc[e + 3];
        a0 += cur[(size_t)i0 * EDIM + lane];
        a1 += cur[(size_t)i1 * EDIM + lane];
        a2 += cur[(size_t)i2 * EDIM + lane];
        a3 += cur[(size_t)i3 * EDIM + lane];
    }
    if (e + 2 <= s1) {
        int i0 = ssrc[e + 0], i1 = ssrc[e + 1];
        a0 += cur[(size_t)i0 * EDIM + lane];
        a1 += cur[(size_t)i1 * EDIM + lane];
        e += 2;
    }
    if (e < s1) a2 += cur[(size_t)ssrc[e] * EDIM + lane];
    nxt[(size_t)w * EDIM + lane] = (a0 + a1) + (a2 + a3);
}

// ---------------- fused sampled accumulation: layers 0+1+2+3 at the 8192 rows ----------------

__global__ void final_acc_k(const float* __restrict__ emb, const float* __restrict__ bufA,
                            const float* __restrict__ bufB, const int* __restrict__ users,
                            const int* __restrict__ items, const int* __restrict__ row_ptr,
                            const int* __restrict__ ssrc, float* __restrict__ accs) {
    int t = (int)(blockIdx.x * blockDim.x + threadIdx.x);
    int w = t >> 6, lane = t & 63;
    if (w >= 2 * BATCH) return;
    int node = (w < BATCH) ? users[w] : (NUM_USERS + items[w - BATCH]);
    size_t o = (size_t)node * EDIM + lane;
    float base = emb[o] + bufA[o] + bufB[o];    // layers 0,1,2
    int s0 = row_ptr[node], s1 = row_ptr[node + 1];
    float a0 = 0.f, a1 = 0.f, a2 = 0.f, a3 = 0.f;
    int e = s0;
    for (; e + 4 <= s1; e += 4) {               // layer 3: gather bufB of in-neighbors
        int i0 = ssrc[e + 0], i1 = ssrc[e + 1], i2 = ssrc[e + 2], i3 = ssrc[e + 3];
        a0 += bufB[(size_t)i0 * EDIM + lane];
        a1 += bufB[(size_t)i1 * EDIM + lane];
        a2 += bufB[(size_t)i2 * EDIM + lane];
        a3 += bufB[(size_t)i3 * EDIM + lane];
    }
    if (e + 2 <= s1) {
        int i0 = ssrc[e + 0], i1 = ssrc[e + 1];
        a0 += bufB[(size_t)i0 * EDIM + lane];
        a1 += bufB[(size_t)i1 * EDIM + lane];
        e += 2;
    }
    if (e < s1) a2 += bufB[(size_t)ssrc[e] * EDIM + lane];
    accs[(size_t)w * EDIM + lane] = base + (a0 + a1) + (a2 + a3);
}

__global__ void dot_out_k(const float* __restrict__ accs, float* __restrict__ out) {
    int t = (int)(blockIdx.x * blockDim.x + threadIdx.x);
    int b = t >> 6, lane = t & 63;
    if (b >= BATCH) return;
    float p = accs[(size_t)b * EDIM + lane] * accs[(size_t)(BATCH + b) * EDIM + lane];
    #pragma unroll
    for (int off = 32; off; off >>= 1) p += __shfl_down(p, off, 64);
    if (lane == 0) out[b] = p * (1.0f / 16.0f);
}

// ---------------- fallback (baseline atomic path) ----------------

__global__ void acc_batch_k(const float* __restrict__ cur, const int* __restrict__ users,
                            const int* __restrict__ items, float* __restrict__ accs, int first) {
    int t = (int)(blockIdx.x * blockDim.x + threadIdx.x);
    int row = t >> 6, lane = t & 63;
    if (row >= 2 * BATCH) return;
    int node = (row < BATCH) ? users[row] : (NUM_USERS + items[row - BATCH]);
    float v = cur[(size_t)node * EDIM + lane];
    size_t o = (size_t)row * EDIM + lane;
    if (first) accs[o] = v;
    else       accs[o] += v;
}

__global__ void scatter_add_k(const float* __restrict__ cur, float* __restrict__ nxt,
                              const int* __restrict__ src, const int* __restrict__ dst) {
    int w = (int)((blockIdx.x * blockDim.x + threadIdx.x) >> 6);
    int lane = threadIdx.x & 63;
    if (w >= NEDGES) return;
    float v = cur[(size_t)src[w] * EDIM + lane];
    atomicAdd(&nxt[(size_t)dst[w] * EDIM + lane], v);
}

extern "C" void kernel_launch(void* const* d_in, const int* in_sizes, int n_in,
                              void* d_out, int out_size, void* d_ws, size_t ws_size,
                              hipStream_t stream) {
    const float* emb   = (const float*)d_in[0];
    const int*   edge  = (const int*)d_in[1];
    const int*   src   = edge;            // edge_index[0]
    const int*   dst   = edge + NEDGES;   // edge_index[1]
    const int*   users = (const int*)d_in[2];
    const int*   items = (const int*)d_in[3];
    float*       out   = (float*)d_out;

    const size_t bufBytes = (size_t)NNODES * EDIM * sizeof(float); // 76.8 MB

    // workspace layout
    size_t off = 0;
    float* bufA = (float*)((char*)d_ws + off); off = align256(off + bufBytes);
    float* bufB = (float*)((char*)d_ws + off); off = align256(off + bufBytes);
    float* accs = (float*)((char*)d_ws + off); off = align256(off + (size_t)2 * BATCH * EDIM * sizeof(float));
    int* row_ptr   = (int*)((char*)d_ws + off); off = align256(off + (size_t)(NNODES + 1) * sizeof(int));
    int* counts    = (int*)((char*)d_ws + off); off = align256(off + (size_t)NNODES * sizeof(int));
    int* cursor    = (int*)((char*)d_ws + off); off = align256(off + (size_t)NNODES * sizeof(int));
    int* chunk_tot = (int*)((char*)d_ws + off); off = align256(off + (size_t)NCHUNKS * sizeof(int));
    int* ssrc      = (int*)((char*)d_ws + off); off = align256(off + (size_t)NEDGES * sizeof(int));
    unsigned char* mS = (unsigned char*)((char*)d_ws + off); off = align256(off + (size_t)NNODES);
    unsigned char* mA = (unsigned char*)((char*)d_ws + off); off = align256(off + (size_t)NNODES);
    unsigned char* mB = (unsigned char*)((char*)d_ws + off); off = align256(off + (size_t)NNODES);
    const size_t needed = off;

    const dim3 blk(256);
    const int edgeBlocks = (NEDGES + 255) / 256;
    const int propBlocks = (NNODES * 64 + 255) / 256;
    const int sampBlocks = (2 * BATCH * 64 + 255) / 256;
    const int dotBlocks  = (BATCH * 64 + 255) / 256;

    if (ws_size >= needed) {
        // ---- CSR build ----
        hipMemsetAsync(counts, 0, (size_t)NNODES * sizeof(int), stream);
        hipMemsetAsync(cursor, 0, (size_t)NNODES * sizeof(int), stream);
        hipMemsetAsync(mS, 0, (size_t)NNODES, stream);
        hipMemsetAsync(mA, 0, (size_t)NNODES, stream);
        hipMemsetAsync(mB, 0, (size_t)NNODES, stream);
        hist_k<<<edgeBlocks, blk, 0, stream>>>(dst, counts);
        scan_chunk_k<<<NCHUNKS, blk, 0, stream>>>(counts, row_ptr, chunk_tot);
        scan_tops_k<<<1, 64, 0, stream>>>(chunk_tot, row_ptr);
        add_off_k<<<(NNODES + 255) / 256, blk, 0, stream>>>(row_ptr, chunk_tot);
        fill_k<<<edgeBlocks, blk, 0, stream>>>(src, dst, row_ptr, cursor, ssrc);

        // ---- frontier marking ----
        mark_sampled_k<<<(2 * BATCH + 255) / 256, blk, 0, stream>>>(users, items, mS);
        markA_k<<<edgeBlocks, blk, 0, stream>>>(src, dst, mS, mA);
        markB_k<<<edgeBlocks, blk, 0, stream>>>(src, dst, mS, mA, mB);

        // ---- layers (layer1 at mS|mA|mB, layer2 at mS|mA, layer3 fused at sampled) ----
        prop_k<<<propBlocks, blk, 0, stream>>>(emb,  bufA, row_ptr, ssrc, mS, mA, mB);
        prop_k<<<propBlocks, blk, 0, stream>>>(bufA, bufB, row_ptr, ssrc, mS, mA, mA);
        final_acc_k<<<sampBlocks, blk, 0, stream>>>(emb, bufA, bufB, users, items, row_ptr, ssrc, accs);
        dot_out_k<<<dotBlocks, blk, 0, stream>>>(accs, out);
    } else {
        // ---- fallback: baseline atomic path ----
        const int scatterBlocks = (NEDGES + 3) / 4;
        acc_batch_k<<<sampBlocks, blk, 0, stream>>>(emb, users, items, accs, 1);
        const float* cur = emb;
        float* bufs[2] = {bufA, bufB};
        for (int l = 0; l < 3; ++l) {
            float* nxt = bufs[l & 1];
            hipMemsetAsync(nxt, 0, bufBytes, stream);
            scatter_add_k<<<scatterBlocks, blk, 0, stream>>>(cur, nxt, src, dst);
            acc_batch_k<<<sampBlocks, blk, 0, stream>>>(nxt, users, items, accs, 0);
            cur = nxt;
        }
        dot_out_k<<<dotBlocks, blk, 0, stream>>>(accs, out);
    }
}